// Round 18
// baseline (121.738 us; speedup 1.0000x reference)
//
#include <hip/hip_runtime.h>

// Problem constants (B=2, W=2048, C=768, H=12, head dim 64)
constexpr int B_  = 2;
constexpr int W_  = 2048;
constexpr int C_  = 768;
constexpr int H_  = 12;
constexpr int HD  = 64;
constexpr int C3  = 3 * C_;           // 2304
constexpr int M_  = B_ * W_;          // 4096
constexpr int NSLOT = 40;             // (128q-qtile, 512key-chunk) pairs/(b,h)

typedef float  f32x4 __attribute__((ext_vector_type(4)));
typedef short  s16x8 __attribute__((ext_vector_type(8)));
typedef short  s16x4 __attribute__((ext_vector_type(4)));
typedef unsigned short u16;
typedef unsigned int   u32;

// fp32 -> bf16 (round-to-nearest-even), bit pattern as ushort
__device__ __forceinline__ u16 f2bf(float f) {
    unsigned int u = __float_as_uint(f);
    u += 0x7FFFu + ((u >> 16) & 1u);
    return (u16)(u >> 16);
}
__device__ __forceinline__ float bf2f(u16 v) {
    return __uint_as_float(((u32)v) << 16);
}

// async global->LDS, 16 bytes per lane. LDS dest = wave-uniform base + lane*16.
__device__ __forceinline__ void gload_lds16(const u16* g, u16* l) {
    __builtin_amdgcn_global_load_lds(
        (const __attribute__((address_space(1))) unsigned int*)g,
        (__attribute__((address_space(3))) unsigned int*)l, 16, 0, 0);
}

// ---------------------------------------------------------------------------
// fp32 -> bf16 bulk convert, all three tensors in one launch (8 elems/thread)
// ---------------------------------------------------------------------------
__global__ __launch_bounds__(256)
void cvt_all(const float* __restrict__ x, const float* __restrict__ wa,
             const float* __restrict__ wp, u16* __restrict__ xb,
             u16* __restrict__ wab, u16* __restrict__ wpb)
{
    const int n0 = M_ * C_ / 8;
    const int n1 = n0 + C3 * C_ / 8;
    const int n2 = n1 + C_ * C_ / 8;
    int i = blockIdx.x * 256 + threadIdx.x;
    const float* s; u16* d; int j;
    if (i < n0)      { s = x;  d = xb;  j = i; }
    else if (i < n1) { s = wa; d = wab; j = i - n0; }
    else if (i < n2) { s = wp; d = wpb; j = i - n1; }
    else return;
    const float4 a = reinterpret_cast<const float4*>(s)[j * 2];
    const float4 b = reinterpret_cast<const float4*>(s)[j * 2 + 1];
    s16x8 v;
    v[0] = (short)f2bf(a.x); v[1] = (short)f2bf(a.y);
    v[2] = (short)f2bf(a.z); v[3] = (short)f2bf(a.w);
    v[4] = (short)f2bf(b.x); v[5] = (short)f2bf(b.y);
    v[6] = (short)f2bf(b.z); v[7] = (short)f2bf(b.w);
    reinterpret_cast<s16x8*>(d)[j] = v;
}

// ---------------------------------------------------------------------------
// bf16 NT GEMM via MFMA (round-17 kernel, unchanged): 128x128, BK=32,
// triple-buffered depth-2 prefetch with counted vmcnt.
// ---------------------------------------------------------------------------
__device__ __forceinline__ void store_out(u16*  p, float v) { *p = f2bf(v); }
__device__ __forceinline__ void store_out(float* p, float v) { *p = v; }

template <typename OutT>
__global__ __launch_bounds__(256)
void gemm_nt_mfma(const u16* __restrict__ A, const u16* __restrict__ Bm,
                  OutT* __restrict__ Y, int Ndim, int Kdim)
{
    __shared__ __align__(16) u16 As[3][128 * 32];
    __shared__ __align__(16) u16 Bs[3][128 * 32];

    const int t  = threadIdx.x;
    const int w  = t >> 6;
    const int l  = t & 63;
    const int lg = l >> 4;
    const int ln = l & 15;
    const int wm = w >> 1;
    const int wn = w & 1;
    const int m0 = blockIdx.x * 128;
    const int n0 = blockIdx.y * 128;

    f32x4 acc[4][4];
    #pragma unroll
    for (int mi = 0; mi < 4; ++mi)
        #pragma unroll
        for (int ni = 0; ni < 4; ++ni)
            acc[mi][ni] = (f32x4){0.f, 0.f, 0.f, 0.f};

    size_t off[2];
    #pragma unroll
    for (int it = 0; it < 2; ++it) {
        const int c  = t + it * 256;
        off[it] = (size_t)((c >> 6) * 16 + (c & 15)) * Kdim + ((c >> 4) & 3) * 8;
    }

    #define GEMM_STAGE(buf, k0s)                                              \
        _Pragma("unroll")                                                     \
        for (int it = 0; it < 2; ++it) {                                      \
            gload_lds16(A  + (size_t)m0 * Kdim + (k0s) + off[it],             \
                        &As[buf][(size_t)(it * 256 + w * 64) * 8]);           \
            gload_lds16(Bm + (size_t)n0 * Kdim + (k0s) + off[it],             \
                        &Bs[buf][(size_t)(it * 256 + w * 64) * 8]);           \
        }

    GEMM_STAGE(0, 0)
    GEMM_STAGE(1, 32)

    int cur = 0;
    for (int k0 = 0; k0 < Kdim; k0 += 32) {
        if (k0 + 32 < Kdim)
            asm volatile("s_waitcnt vmcnt(4)" ::: "memory");
        else
            asm volatile("s_waitcnt vmcnt(0)" ::: "memory");
        __builtin_amdgcn_s_barrier();

        const int nx2 = (cur + 2 >= 3) ? cur - 1 : cur + 2;
        if (k0 + 64 < Kdim) { GEMM_STAGE(nx2, k0 + 64) }

        s16x8 af[4], bf[4];
        #pragma unroll
        for (int mi = 0; mi < 4; ++mi)
            af[mi] = *reinterpret_cast<const s16x8*>(
                &As[cur][(size_t)((wm * 4 + mi) * 64 + l) * 8]);
        #pragma unroll
        for (int ni = 0; ni < 4; ++ni)
            bf[ni] = *reinterpret_cast<const s16x8*>(
                &Bs[cur][(size_t)((wn * 4 + ni) * 64 + l) * 8]);
        #pragma unroll
        for (int mi = 0; mi < 4; ++mi)
            #pragma unroll
            for (int ni = 0; ni < 4; ++ni)
                acc[mi][ni] = __builtin_amdgcn_mfma_f32_16x16x32_bf16(
                    af[mi], bf[ni], acc[mi][ni], 0, 0, 0);

        cur = (cur == 2) ? 0 : cur + 1;
    }
    #undef GEMM_STAGE

    #pragma unroll
    for (int mi = 0; mi < 4; ++mi) {
        const int row = m0 + wm * 64 + mi * 16 + lg * 4;
        #pragma unroll
        for (int ni = 0; ni < 4; ++ni) {
            const int col = n0 + wn * 64 + ni * 16 + ln;
            #pragma unroll
            for (int r = 0; r < 4; ++r)
                store_out(&Y[(size_t)(row + r) * Ndim + col], acc[mi][ni][r]);
        }
    }
}

// ---------------------------------------------------------------------------
// KV-split MFMA causal flash attention, partial pass, v9: 128 QUERIES/BLOCK
// (32 q/wave as 2 m-frags). The per-tile fixed costs (K/V staging, shared
// kf/vf LDS fragment reads, 2 barriers) now serve 2x the MFMA work; kf/vf
// fragments are read ONCE and used by BOTH m-frags. Total tiles staged
// across the grid halves -> FETCH drops ~2x.
// Slot table (per (b,h), 40 slots): qt<4:1 chunk; <8:2; <12:3; else 4.
// Everything else carried from the validated round-16 body: fragment-major
// K, conflict-free V^T staging, swapped QK^T, lane-local P, cvt_pk,
// mask-free fast path, ones-MFMA row-sum, bf16 po, biggest-first.
// ---------------------------------------------------------------------------
__global__ __launch_bounds__(256)
void attn_partial(const u16* __restrict__ qkv, u16* __restrict__ po,
                  float* __restrict__ pl)
{
    __shared__ __align__(16) unsigned char KsB[64 * 128];       // 8 KiB
    __shared__ __align__(16) unsigned char VtB[64 * 144];       // 9 KiB

    const int t  = threadIdx.x;
    const int w  = t >> 6;
    const int l  = t & 63;
    const int lg = l >> 4;
    const int ln = l & 15;
    const int p  = (NSLOT - 1) - (int)blockIdx.x;   // biggest-first
    const int h  = blockIdx.y;
    const int b  = blockIdx.z;

    int qt, ck;
    if (p < 4)       { qt = p;                  ck = 0; }
    else if (p < 12) { qt = 4  + ((p - 4) >> 1);  ck = (p - 4) & 1; }
    else if (p < 24) { qt = 8  + (p - 12) / 3;    ck = (p - 12) % 3; }
    else             { qt = 12 + ((p - 24) >> 2); ck = (p - 24) & 3; }

    const int qb  = qt * 128;
    const int q0w = qb + w * 32;                // wave's first query (of 32)
    const int g0  = ck * 8;                     // first 64-key tile
    const int g1  = min(2 * (qt + 1), g0 + 8);  // one past last tile
    const int slot = (b * H_ + h) * NSLOT + p;

    const u16* base  = qkv + (size_t)(b * W_) * C3;
    const u16* kbase = base + C_ + h * HD;
    const u16* vbase = base + 2 * C_ + h * HD;

    // Hoisted Q fragments, 2 m-frags (B operand: col=ln -> q = q0w+m*16+ln)
    s16x8 qf[2][2];
    #pragma unroll
    for (int m = 0; m < 2; ++m) {
        const u16* qrow = base + (size_t)(q0w + m * 16 + ln) * C3 + h * HD;
        #pragma unroll
        for (int kc = 0; kc < 2; ++kc)
            qf[m][kc] = *reinterpret_cast<const s16x8*>(&qrow[kc * 32 + lg * 8]);
    }

    s16x8 onesf;
    {
        const short v1 = (ln == 0) ? (short)0x3F80 : (short)0;
        #pragma unroll
        for (int i = 0; i < 8; ++i) onesf[i] = v1;
    }

    f32x4 o[2][4];
    #pragma unroll
    for (int m = 0; m < 2; ++m)
        #pragma unroll
        for (int i = 0; i < 4; ++i) o[m][i] = (f32x4){0.f, 0.f, 0.f, 0.f};
    f32x4 o4[2] = { (f32x4){0.f,0.f,0.f,0.f}, (f32x4){0.f,0.f,0.f,0.f} };

    const float c1 = 0.18033688011112042f;   // (1/8) * log2(e)
    const float c2 = 17.312340490667562f;    // 12  * log2(e)

    const size_t sk_off = (size_t)((t >> 7) * 16 + (t & 15)) * C3
                        + ((t >> 6) & 1) * 32 + ((t >> 4) & 3) * 8;
    const bool vstage = (t < 128);
    const int vrun = (t >> 4) & 7;
    const int vK0  = (vrun >> 2) * 32 + (vrun & 3) * 4;
    const int vdq  = (t & 15) * 4;
    const int kfb  = l * 16;

    s16x8 kr[2];
    s16x4 vr[8];

    {
        const int s0 = g0 * 64;
        const u16* ks = kbase + (size_t)s0 * C3 + sk_off;
        kr[0] = *reinterpret_cast<const s16x8*>(ks);
        kr[1] = *reinterpret_cast<const s16x8*>(ks + (size_t)32 * C3);
        if (vstage) {
            const u16* vsrc = vbase + (size_t)(s0 + vK0) * C3 + vdq;
            #pragma unroll
            for (int e = 0; e < 8; ++e)
                vr[e] = *reinterpret_cast<const s16x4*>(
                    &vsrc[(size_t)((e >> 2) * 16 + (e & 3)) * C3]);
        }
    }

    for (int g = g0; g < g1; ++g) {
        const int s0 = g * 64;

        __syncthreads();

        *reinterpret_cast<s16x8*>(KsB + t * 16)         = kr[0];
        *reinterpret_cast<s16x8*>(KsB + (t + 256) * 16) = kr[1];
        if (vstage) {
            #pragma unroll
            for (int j = 0; j < 4; ++j) {
                s16x8 pk = { vr[0][j], vr[1][j], vr[2][j], vr[3][j],
                             vr[4][j], vr[5][j], vr[6][j], vr[7][j] };
                *reinterpret_cast<s16x8*>(
                    VtB + (vdq + j) * 144 + vrun * 16) = pk;
            }
        }

        if (g + 1 < g1) {
            const int s1 = s0 + 64;
            const u16* ks = kbase + (size_t)s1 * C3 + sk_off;
            kr[0] = *reinterpret_cast<const s16x8*>(ks);
            kr[1] = *reinterpret_cast<const s16x8*>(ks + (size_t)32 * C3);
            if (vstage) {
                const u16* vsrc = vbase + (size_t)(s1 + vK0) * C3 + vdq;
                #pragma unroll
                for (int e = 0; e < 8; ++e)
                    vr[e] = *reinterpret_cast<const s16x4*>(
                        &vsrc[(size_t)((e >> 2) * 16 + (e & 3)) * C3]);
            }
        }

        __syncthreads();

        #pragma unroll
        for (int c = 0; c < 2; ++c) {
            if (s0 + c * 32 <= q0w + 31) {       // any m-frag active (uniform)
                const bool act0 = (s0 + c * 32 <= q0w + 15);
                float pt[2][2][4];
                #pragma unroll
                for (int n2 = 0; n2 < 2; ++n2) {
                    // shared K fragments: read once, used by both m-frags
                    const unsigned char* kfrag = KsB + (c * 2 + n2) * 2048 + kfb;
                    s16x8 kf0 = *reinterpret_cast<const s16x8*>(kfrag);
                    s16x8 kf1 = *reinterpret_cast<const s16x8*>(kfrag + 1024);
                    #pragma unroll
                    for (int m = 0; m < 2; ++m) {
                        if (m == 1 || act0) {
                            f32x4 s = (f32x4){0.f, 0.f, 0.f, 0.f};
                            __builtin_amdgcn_s_setprio(1);
                            s = __builtin_amdgcn_mfma_f32_16x16x32_bf16(
                                kf0, qf[m][0], s, 0, 0, 0);
                            s = __builtin_amdgcn_mfma_f32_16x16x32_bf16(
                                kf1, qf[m][1], s, 0, 0, 0);
                            __builtin_amdgcn_s_setprio(0);
                            const int kg0   = s0 + c * 32 + n2 * 16 + lg * 4;
                            const int klast = s0 + c * 32 + n2 * 16 + 15;
                            const int qbase = q0w + m * 16;
                            if (klast <= qbase) {
                                #pragma unroll
                                for (int r = 0; r < 4; ++r)
                                    pt[m][n2][r] = exp2f(fmaf(s[r], c1, -c2));
                            } else {
                                const int qg = qbase + ln;
                                #pragma unroll
                                for (int r = 0; r < 4; ++r)
                                    pt[m][n2][r] = (kg0 + r <= qg)
                                              ? exp2f(fmaf(s[r], c1, -c2)) : 0.0f;
                            }
                        }
                    }
                }
                // shared V fragments: read once, used by both m-frags
                s16x8 vf[4];
                #pragma unroll
                for (int dt = 0; dt < 4; ++dt)
                    vf[dt] = *reinterpret_cast<const s16x8*>(
                        VtB + (dt * 16 + ln) * 144 + c * 64 + lg * 16);
                #pragma unroll
                for (int m = 0; m < 2; ++m) {
                    if (m == 1 || act0) {
                        union { s16x8 v; u32 wd[4]; } afu;
                        asm("v_cvt_pk_bf16_f32 %0, %1, %2"
                            : "=v"(afu.wd[0]) : "v"(pt[m][0][0]), "v"(pt[m][0][1]));
                        asm("v_cvt_pk_bf16_f32 %0, %1, %2"
                            : "=v"(afu.wd[1]) : "v"(pt[m][0][2]), "v"(pt[m][0][3]));
                        asm("v_cvt_pk_bf16_f32 %0, %1, %2"
                            : "=v"(afu.wd[2]) : "v"(pt[m][1][0]), "v"(pt[m][1][1]));
                        asm("v_cvt_pk_bf16_f32 %0, %1, %2"
                            : "=v"(afu.wd[3]) : "v"(pt[m][1][2]), "v"(pt[m][1][3]));
                        const s16x8 af = afu.v;
                        __builtin_amdgcn_s_setprio(1);
                        #pragma unroll
                        for (int dt = 0; dt < 4; ++dt)
                            o[m][dt] = __builtin_amdgcn_mfma_f32_16x16x32_bf16(
                                af, vf[dt], o[m][dt], 0, 0, 0);
                        o4[m] = __builtin_amdgcn_mfma_f32_16x16x32_bf16(
                            af, onesf, o4[m], 0, 0, 0);
                        __builtin_amdgcn_s_setprio(0);
                    }
                }
            }
        }
    }

    // ---- epilogue ----
    #pragma unroll
    for (int m = 0; m < 2; ++m) {
        if (ln == 0) {
            #pragma unroll
            for (int r = 0; r < 4; ++r)
                pl[(size_t)slot * 128 + w * 32 + m * 16 + lg * 4 + r] = o4[m][r];
        }
        u16* os = po + (size_t)slot * 8192;
        #pragma unroll
        for (int r = 0; r < 4; ++r)
            #pragma unroll
            for (int dt = 0; dt < 4; ++dt)
                os[(w * 32 + m * 16 + lg * 4 + r) * 64 + dt * 16 + ln] =
                    f2bf(o[m][dt][r]);
    }
}

// ---------------------------------------------------------------------------
// Combine pass: per 128-q tile, sum <=4 bf16 chunk partials, normalize.
// ---------------------------------------------------------------------------
__global__ __launch_bounds__(256)
void attn_combine(const u16* __restrict__ po, const float* __restrict__ pl,
                  u16* __restrict__ aob)
{
    const int qt = blockIdx.x;          // 0..15
    const int h  = blockIdx.y;
    const int b  = blockIdx.z;
    const int nc = (qt + 4) >> 2;
    int cum;
    if (qt < 4)       cum = qt;
    else if (qt < 8)  cum = 4  + 2 * (qt - 4);
    else if (qt < 12) cum = 12 + 3 * (qt - 8);
    else              cum = 24 + 4 * (qt - 12);
    const int slot0 = (b * H_ + h) * NSLOT + cum;

    const int tid = threadIdx.x;
    const int i   = tid >> 1;          // query row in tile (0..127)
    const int d0  = (tid & 1) * 32;    // 32 dims per thread

    float acc[32] = {};
    float lt = 0.0f;
    for (int c = 0; c < nc; ++c) {
        const u16* os = po + (size_t)(slot0 + c) * 8192 + i * 64 + d0;
        #pragma unroll
        for (int v = 0; v < 4; ++v) {
            s16x8 vv = *reinterpret_cast<const s16x8*>(os + v * 8);
            #pragma unroll
            for (int e = 0; e < 8; ++e) acc[v * 8 + e] += bf2f((u16)vv[e]);
        }
        lt += pl[(size_t)(slot0 + c) * 128 + i];
    }
    const float inv = 1.0f / lt;

    u16* dst = aob + (size_t)(b * W_ + qt * 128 + i) * C_ + h * HD + d0;
    #pragma unroll
    for (int v = 0; v < 4; ++v) {
        s16x8 ov;
        #pragma unroll
        for (int e = 0; e < 8; ++e) ov[e] = (short)f2bf(acc[v * 8 + e] * inv);
        *reinterpret_cast<s16x8*>(dst + v * 8) = ov;
    }
}

// ---------------------------------------------------------------------------
extern "C" void kernel_launch(void* const* d_in, const int* in_sizes, int n_in,
                              void* d_out, int out_size, void* d_ws, size_t ws_size,
                              hipStream_t stream)
{
    const float* x      = (const float*)d_in[0];  // [B,W,C]
    const float* w_attn = (const float*)d_in[1];  // [3C,C]
    const float* w_proj = (const float*)d_in[2];  // [C,C]
    float* out = (float*)d_out;                   // [B,W,C]

    u16* xb   = (u16*)d_ws;                       // [M,  C]
    u16* wab  = xb   + (size_t)M_ * C_;           // [3C, C]
    u16* wpb  = wab  + (size_t)C3 * C_;           // [C,  C]
    u16* qkvb = wpb  + (size_t)C_ * C_;           // [M, 3C]
    u16* aob  = qkvb + (size_t)M_ * C3;           // [M,  C]
    u16* po   = aob  + (size_t)M_ * C_;           // [960][8192] bf16 15.7 MB
    float* pl = (float*)(po + (size_t)B_ * H_ * NSLOT * 8192);  // [960][128]

    // 0) fp32 -> bf16 conversions (single launch)
    {
        const int total8 = (M_ * C_ + C3 * C_ + C_ * C_) / 8;
        cvt_all<<<(total8 + 255) / 256, 256, 0, stream>>>(
            x, w_attn, w_proj, xb, wab, wpb);
    }

    // 1) QKV projection (bf16 MFMA, 128x128, BK=32, depth-2 prefetch)
    {
        dim3 grid(M_ / 128, C3 / 128);
        gemm_nt_mfma<u16><<<grid, 256, 0, stream>>>(xb, wab, qkvb, C3, C_);
    }

    // 2a) KV-split attention partials (960 blocks, 128 q/block, biggest-first)
    {
        dim3 grid(NSLOT, H_, B_);
        attn_partial<<<grid, 256, 0, stream>>>(qkvb, po, pl);
    }
    // 2b) combine + normalize
    {
        dim3 grid(W_ / 128, H_, B_);
        attn_combine<<<grid, 256, 0, stream>>>(po, pl, aob);
    }

    // 3) Output projection: out = aob @ wpb^T (fp32 out)
    {
        dim3 grid(M_ / 128, C_ / 128);
        gemm_nt_mfma<float><<<grid, 256, 0, stream>>>(aob, wpb, out, C_, C_);
    }
}

// Round 19
// 120.803 us; speedup vs baseline: 1.0077x; 1.0077x over previous
//
#include <hip/hip_runtime.h>

// Problem constants (B=2, W=2048, C=768, H=12, head dim 64)
constexpr int B_  = 2;
constexpr int W_  = 2048;
constexpr int C_  = 768;
constexpr int H_  = 12;
constexpr int HD  = 64;
constexpr int C3  = 3 * C_;           // 2304
constexpr int M_  = B_ * W_;          // 4096
constexpr int NSLOT = 72;             // (128q-qtile, 256key-chunk) pairs/(b,h)

typedef float  f32x4 __attribute__((ext_vector_type(4)));
typedef short  s16x8 __attribute__((ext_vector_type(8)));
typedef short  s16x4 __attribute__((ext_vector_type(4)));
typedef unsigned short u16;
typedef unsigned int   u32;

// fp32 -> bf16 (round-to-nearest-even), bit pattern as ushort
__device__ __forceinline__ u16 f2bf(float f) {
    unsigned int u = __float_as_uint(f);
    u += 0x7FFFu + ((u >> 16) & 1u);
    return (u16)(u >> 16);
}
__device__ __forceinline__ float bf2f(u16 v) {
    return __uint_as_float(((u32)v) << 16);
}

// async global->LDS, 16 bytes per lane. LDS dest = wave-uniform base + lane*16.
__device__ __forceinline__ void gload_lds16(const u16* g, u16* l) {
    __builtin_amdgcn_global_load_lds(
        (const __attribute__((address_space(1))) unsigned int*)g,
        (__attribute__((address_space(3))) unsigned int*)l, 16, 0, 0);
}

// ---------------------------------------------------------------------------
// fp32 -> bf16 bulk convert, all three tensors in one launch (8 elems/thread)
// ---------------------------------------------------------------------------
__global__ __launch_bounds__(256)
void cvt_all(const float* __restrict__ x, const float* __restrict__ wa,
             const float* __restrict__ wp, u16* __restrict__ xb,
             u16* __restrict__ wab, u16* __restrict__ wpb)
{
    const int n0 = M_ * C_ / 8;
    const int n1 = n0 + C3 * C_ / 8;
    const int n2 = n1 + C_ * C_ / 8;
    int i = blockIdx.x * 256 + threadIdx.x;
    const float* s; u16* d; int j;
    if (i < n0)      { s = x;  d = xb;  j = i; }
    else if (i < n1) { s = wa; d = wab; j = i - n0; }
    else if (i < n2) { s = wp; d = wpb; j = i - n1; }
    else return;
    const float4 a = reinterpret_cast<const float4*>(s)[j * 2];
    const float4 b = reinterpret_cast<const float4*>(s)[j * 2 + 1];
    s16x8 v;
    v[0] = (short)f2bf(a.x); v[1] = (short)f2bf(a.y);
    v[2] = (short)f2bf(a.z); v[3] = (short)f2bf(a.w);
    v[4] = (short)f2bf(b.x); v[5] = (short)f2bf(b.y);
    v[6] = (short)f2bf(b.z); v[7] = (short)f2bf(b.w);
    reinterpret_cast<s16x8*>(d)[j] = v;
}

// ---------------------------------------------------------------------------
// bf16 NT GEMM via MFMA (round-17 kernel, unchanged): 128x128, BK=32,
// triple-buffered depth-2 prefetch with counted vmcnt.
// ---------------------------------------------------------------------------
__device__ __forceinline__ void store_out(u16*  p, float v) { *p = f2bf(v); }
__device__ __forceinline__ void store_out(float* p, float v) { *p = v; }

template <typename OutT>
__global__ __launch_bounds__(256)
void gemm_nt_mfma(const u16* __restrict__ A, const u16* __restrict__ Bm,
                  OutT* __restrict__ Y, int Ndim, int Kdim)
{
    __shared__ __align__(16) u16 As[3][128 * 32];
    __shared__ __align__(16) u16 Bs[3][128 * 32];

    const int t  = threadIdx.x;
    const int w  = t >> 6;
    const int l  = t & 63;
    const int lg = l >> 4;
    const int ln = l & 15;
    const int wm = w >> 1;
    const int wn = w & 1;
    const int m0 = blockIdx.x * 128;
    const int n0 = blockIdx.y * 128;

    f32x4 acc[4][4];
    #pragma unroll
    for (int mi = 0; mi < 4; ++mi)
        #pragma unroll
        for (int ni = 0; ni < 4; ++ni)
            acc[mi][ni] = (f32x4){0.f, 0.f, 0.f, 0.f};

    size_t off[2];
    #pragma unroll
    for (int it = 0; it < 2; ++it) {
        const int c  = t + it * 256;
        off[it] = (size_t)((c >> 6) * 16 + (c & 15)) * Kdim + ((c >> 4) & 3) * 8;
    }

    #define GEMM_STAGE(buf, k0s)                                              \
        _Pragma("unroll")                                                     \
        for (int it = 0; it < 2; ++it) {                                      \
            gload_lds16(A  + (size_t)m0 * Kdim + (k0s) + off[it],             \
                        &As[buf][(size_t)(it * 256 + w * 64) * 8]);           \
            gload_lds16(Bm + (size_t)n0 * Kdim + (k0s) + off[it],             \
                        &Bs[buf][(size_t)(it * 256 + w * 64) * 8]);           \
        }

    GEMM_STAGE(0, 0)
    GEMM_STAGE(1, 32)

    int cur = 0;
    for (int k0 = 0; k0 < Kdim; k0 += 32) {
        if (k0 + 32 < Kdim)
            asm volatile("s_waitcnt vmcnt(4)" ::: "memory");
        else
            asm volatile("s_waitcnt vmcnt(0)" ::: "memory");
        __builtin_amdgcn_s_barrier();

        const int nx2 = (cur + 2 >= 3) ? cur - 1 : cur + 2;
        if (k0 + 64 < Kdim) { GEMM_STAGE(nx2, k0 + 64) }

        s16x8 af[4], bf[4];
        #pragma unroll
        for (int mi = 0; mi < 4; ++mi)
            af[mi] = *reinterpret_cast<const s16x8*>(
                &As[cur][(size_t)((wm * 4 + mi) * 64 + l) * 8]);
        #pragma unroll
        for (int ni = 0; ni < 4; ++ni)
            bf[ni] = *reinterpret_cast<const s16x8*>(
                &Bs[cur][(size_t)((wn * 4 + ni) * 64 + l) * 8]);
        #pragma unroll
        for (int mi = 0; mi < 4; ++mi)
            #pragma unroll
            for (int ni = 0; ni < 4; ++ni)
                acc[mi][ni] = __builtin_amdgcn_mfma_f32_16x16x32_bf16(
                    af[mi], bf[ni], acc[mi][ni], 0, 0, 0);

        cur = (cur == 2) ? 0 : cur + 1;
    }
    #undef GEMM_STAGE

    #pragma unroll
    for (int mi = 0; mi < 4; ++mi) {
        const int row = m0 + wm * 64 + mi * 16 + lg * 4;
        #pragma unroll
        for (int ni = 0; ni < 4; ++ni) {
            const int col = n0 + wn * 64 + ni * 16 + ln;
            #pragma unroll
            for (int r = 0; r < 4; ++r)
                store_out(&Y[(size_t)(row + r) * Ndim + col], acc[mi][ni][r]);
        }
    }
}

// ---------------------------------------------------------------------------
// KV-split MFMA causal flash attention, partial pass, v10: 128 q/block
// (round-18 amortization: shared kf/vf reads + staging serve 2 m-frags)
// with 256-KEY CHUNKS -> 72 slots/(b,h) = 1728 blocks (6.75/CU), worst
// block 4 tiles. Restores round-16's parallelism while keeping round-18's
// halved per-query fixed costs. Total staged tiles invariant (FETCH ~same).
// Slot layout: nch(qt) = (qt>>1)+1; cum(2a)=a(a+1), cum(2a+1)=(a+1)^2.
// ---------------------------------------------------------------------------
__global__ __launch_bounds__(256)
void attn_partial(const u16* __restrict__ qkv, u16* __restrict__ po,
                  float* __restrict__ pl)
{
    __shared__ __align__(16) unsigned char KsB[64 * 128];       // 8 KiB
    __shared__ __align__(16) unsigned char VtB[64 * 144];       // 9 KiB

    const int t  = threadIdx.x;
    const int w  = t >> 6;
    const int l  = t & 63;
    const int lg = l >> 4;
    const int ln = l & 15;
    const int p  = (NSLOT - 1) - (int)blockIdx.x;   // biggest-first
    const int h  = blockIdx.y;
    const int b  = blockIdx.z;

    // p -> (qt, ck): scalar loop over 16 qtiles (negligible)
    int qt = 0, cumv = 0;
    while (cumv + ((qt >> 1) + 1) <= p) { cumv += (qt >> 1) + 1; ++qt; }
    const int ck = p - cumv;

    const int qb  = qt * 128;
    const int q0w = qb + w * 32;                // wave's first query (of 32)
    const int g0  = ck * 4;                     // first 64-key tile
    const int g1  = min(2 * (qt + 1), g0 + 4);  // one past last tile
    const int slot = (b * H_ + h) * NSLOT + p;

    const u16* base  = qkv + (size_t)(b * W_) * C3;
    const u16* kbase = base + C_ + h * HD;
    const u16* vbase = base + 2 * C_ + h * HD;

    // Hoisted Q fragments, 2 m-frags (B operand: col=ln -> q = q0w+m*16+ln)
    s16x8 qf[2][2];
    #pragma unroll
    for (int m = 0; m < 2; ++m) {
        const u16* qrow = base + (size_t)(q0w + m * 16 + ln) * C3 + h * HD;
        #pragma unroll
        for (int kc = 0; kc < 2; ++kc)
            qf[m][kc] = *reinterpret_cast<const s16x8*>(&qrow[kc * 32 + lg * 8]);
    }

    s16x8 onesf;
    {
        const short v1 = (ln == 0) ? (short)0x3F80 : (short)0;
        #pragma unroll
        for (int i = 0; i < 8; ++i) onesf[i] = v1;
    }

    f32x4 o[2][4];
    #pragma unroll
    for (int m = 0; m < 2; ++m)
        #pragma unroll
        for (int i = 0; i < 4; ++i) o[m][i] = (f32x4){0.f, 0.f, 0.f, 0.f};
    f32x4 o4[2] = { (f32x4){0.f,0.f,0.f,0.f}, (f32x4){0.f,0.f,0.f,0.f} };

    const float c1 = 0.18033688011112042f;   // (1/8) * log2(e)
    const float c2 = 17.312340490667562f;    // 12  * log2(e)

    const size_t sk_off = (size_t)((t >> 7) * 16 + (t & 15)) * C3
                        + ((t >> 6) & 1) * 32 + ((t >> 4) & 3) * 8;
    const bool vstage = (t < 128);
    const int vrun = (t >> 4) & 7;
    const int vK0  = (vrun >> 2) * 32 + (vrun & 3) * 4;
    const int vdq  = (t & 15) * 4;
    const int kfb  = l * 16;

    s16x8 kr[2];
    s16x4 vr[8];

    {
        const int s0 = g0 * 64;
        const u16* ks = kbase + (size_t)s0 * C3 + sk_off;
        kr[0] = *reinterpret_cast<const s16x8*>(ks);
        kr[1] = *reinterpret_cast<const s16x8*>(ks + (size_t)32 * C3);
        if (vstage) {
            const u16* vsrc = vbase + (size_t)(s0 + vK0) * C3 + vdq;
            #pragma unroll
            for (int e = 0; e < 8; ++e)
                vr[e] = *reinterpret_cast<const s16x4*>(
                    &vsrc[(size_t)((e >> 2) * 16 + (e & 3)) * C3]);
        }
    }

    for (int g = g0; g < g1; ++g) {
        const int s0 = g * 64;

        __syncthreads();

        *reinterpret_cast<s16x8*>(KsB + t * 16)         = kr[0];
        *reinterpret_cast<s16x8*>(KsB + (t + 256) * 16) = kr[1];
        if (vstage) {
            #pragma unroll
            for (int j = 0; j < 4; ++j) {
                s16x8 pk = { vr[0][j], vr[1][j], vr[2][j], vr[3][j],
                             vr[4][j], vr[5][j], vr[6][j], vr[7][j] };
                *reinterpret_cast<s16x8*>(
                    VtB + (vdq + j) * 144 + vrun * 16) = pk;
            }
        }

        if (g + 1 < g1) {
            const int s1 = s0 + 64;
            const u16* ks = kbase + (size_t)s1 * C3 + sk_off;
            kr[0] = *reinterpret_cast<const s16x8*>(ks);
            kr[1] = *reinterpret_cast<const s16x8*>(ks + (size_t)32 * C3);
            if (vstage) {
                const u16* vsrc = vbase + (size_t)(s1 + vK0) * C3 + vdq;
                #pragma unroll
                for (int e = 0; e < 8; ++e)
                    vr[e] = *reinterpret_cast<const s16x4*>(
                        &vsrc[(size_t)((e >> 2) * 16 + (e & 3)) * C3]);
            }
        }

        __syncthreads();

        #pragma unroll
        for (int c = 0; c < 2; ++c) {
            if (s0 + c * 32 <= q0w + 31) {       // any m-frag active (uniform)
                const bool act0 = (s0 + c * 32 <= q0w + 15);
                float pt[2][2][4];
                #pragma unroll
                for (int n2 = 0; n2 < 2; ++n2) {
                    // shared K fragments: read once, used by both m-frags
                    const unsigned char* kfrag = KsB + (c * 2 + n2) * 2048 + kfb;
                    s16x8 kf0 = *reinterpret_cast<const s16x8*>(kfrag);
                    s16x8 kf1 = *reinterpret_cast<const s16x8*>(kfrag + 1024);
                    #pragma unroll
                    for (int m = 0; m < 2; ++m) {
                        if (m == 1 || act0) {
                            f32x4 s = (f32x4){0.f, 0.f, 0.f, 0.f};
                            __builtin_amdgcn_s_setprio(1);
                            s = __builtin_amdgcn_mfma_f32_16x16x32_bf16(
                                kf0, qf[m][0], s, 0, 0, 0);
                            s = __builtin_amdgcn_mfma_f32_16x16x32_bf16(
                                kf1, qf[m][1], s, 0, 0, 0);
                            __builtin_amdgcn_s_setprio(0);
                            const int kg0   = s0 + c * 32 + n2 * 16 + lg * 4;
                            const int klast = s0 + c * 32 + n2 * 16 + 15;
                            const int qbase = q0w + m * 16;
                            if (klast <= qbase) {
                                #pragma unroll
                                for (int r = 0; r < 4; ++r)
                                    pt[m][n2][r] = exp2f(fmaf(s[r], c1, -c2));
                            } else {
                                const int qg = qbase + ln;
                                #pragma unroll
                                for (int r = 0; r < 4; ++r)
                                    pt[m][n2][r] = (kg0 + r <= qg)
                                              ? exp2f(fmaf(s[r], c1, -c2)) : 0.0f;
                            }
                        }
                    }
                }
                // shared V fragments: read once, used by both m-frags
                s16x8 vf[4];
                #pragma unroll
                for (int dt = 0; dt < 4; ++dt)
                    vf[dt] = *reinterpret_cast<const s16x8*>(
                        VtB + (dt * 16 + ln) * 144 + c * 64 + lg * 16);
                #pragma unroll
                for (int m = 0; m < 2; ++m) {
                    if (m == 1 || act0) {
                        union { s16x8 v; u32 wd[4]; } afu;
                        asm("v_cvt_pk_bf16_f32 %0, %1, %2"
                            : "=v"(afu.wd[0]) : "v"(pt[m][0][0]), "v"(pt[m][0][1]));
                        asm("v_cvt_pk_bf16_f32 %0, %1, %2"
                            : "=v"(afu.wd[1]) : "v"(pt[m][0][2]), "v"(pt[m][0][3]));
                        asm("v_cvt_pk_bf16_f32 %0, %1, %2"
                            : "=v"(afu.wd[2]) : "v"(pt[m][1][0]), "v"(pt[m][1][1]));
                        asm("v_cvt_pk_bf16_f32 %0, %1, %2"
                            : "=v"(afu.wd[3]) : "v"(pt[m][1][2]), "v"(pt[m][1][3]));
                        const s16x8 af = afu.v;
                        __builtin_amdgcn_s_setprio(1);
                        #pragma unroll
                        for (int dt = 0; dt < 4; ++dt)
                            o[m][dt] = __builtin_amdgcn_mfma_f32_16x16x32_bf16(
                                af, vf[dt], o[m][dt], 0, 0, 0);
                        o4[m] = __builtin_amdgcn_mfma_f32_16x16x32_bf16(
                            af, onesf, o4[m], 0, 0, 0);
                        __builtin_amdgcn_s_setprio(0);
                    }
                }
            }
        }
    }

    // ---- epilogue ----
    #pragma unroll
    for (int m = 0; m < 2; ++m) {
        if (ln == 0) {
            #pragma unroll
            for (int r = 0; r < 4; ++r)
                pl[(size_t)slot * 128 + w * 32 + m * 16 + lg * 4 + r] = o4[m][r];
        }
        u16* os = po + (size_t)slot * 8192;
        #pragma unroll
        for (int r = 0; r < 4; ++r)
            #pragma unroll
            for (int dt = 0; dt < 4; ++dt)
                os[(w * 32 + m * 16 + lg * 4 + r) * 64 + dt * 16 + ln] =
                    f2bf(o[m][dt][r]);
    }
}

// ---------------------------------------------------------------------------
// Combine pass: per 128-q tile, sum <=8 bf16 chunk partials, normalize.
// ---------------------------------------------------------------------------
__global__ __launch_bounds__(256)
void attn_combine(const u16* __restrict__ po, const float* __restrict__ pl,
                  u16* __restrict__ aob)
{
    const int qt = blockIdx.x;          // 0..15
    const int h  = blockIdx.y;
    const int b  = blockIdx.z;
    const int a  = qt >> 1;
    const int nc = a + 1;                               // chunks for this qt
    const int cum = (qt & 1) ? (a + 1) * (a + 1) : a * (a + 1);
    const int slot0 = (b * H_ + h) * NSLOT + cum;

    const int tid = threadIdx.x;
    const int i   = tid >> 1;          // query row in tile (0..127)
    const int d0  = (tid & 1) * 32;    // 32 dims per thread

    float acc[32] = {};
    float lt = 0.0f;
    for (int c = 0; c < nc; ++c) {
        const u16* os = po + (size_t)(slot0 + c) * 8192 + i * 64 + d0;
        #pragma unroll
        for (int v = 0; v < 4; ++v) {
            s16x8 vv = *reinterpret_cast<const s16x8*>(os + v * 8);
            #pragma unroll
            for (int e = 0; e < 8; ++e) acc[v * 8 + e] += bf2f((u16)vv[e]);
        }
        lt += pl[(size_t)(slot0 + c) * 128 + i];
    }
    const float inv = 1.0f / lt;

    u16* dst = aob + (size_t)(b * W_ + qt * 128 + i) * C_ + h * HD + d0;
    #pragma unroll
    for (int v = 0; v < 4; ++v) {
        s16x8 ov;
        #pragma unroll
        for (int e = 0; e < 8; ++e) ov[e] = (short)f2bf(acc[v * 8 + e] * inv);
        *reinterpret_cast<s16x8*>(dst + v * 8) = ov;
    }
}

// ---------------------------------------------------------------------------
extern "C" void kernel_launch(void* const* d_in, const int* in_sizes, int n_in,
                              void* d_out, int out_size, void* d_ws, size_t ws_size,
                              hipStream_t stream)
{
    const float* x      = (const float*)d_in[0];  // [B,W,C]
    const float* w_attn = (const float*)d_in[1];  // [3C,C]
    const float* w_proj = (const float*)d_in[2];  // [C,C]
    float* out = (float*)d_out;                   // [B,W,C]

    u16* xb   = (u16*)d_ws;                       // [M,  C]
    u16* wab  = xb   + (size_t)M_ * C_;           // [3C, C]
    u16* wpb  = wab  + (size_t)C3 * C_;           // [C,  C]
    u16* qkvb = wpb  + (size_t)C_ * C_;           // [M, 3C]
    u16* aob  = qkvb + (size_t)M_ * C3;           // [M,  C]
    u16* po   = aob  + (size_t)M_ * C_;           // [1728][8192] bf16 28.3 MB
    float* pl = (float*)(po + (size_t)B_ * H_ * NSLOT * 8192);  // [1728][128]

    // 0) fp32 -> bf16 conversions (single launch)
    {
        const int total8 = (M_ * C_ + C3 * C_ + C_ * C_) / 8;
        cvt_all<<<(total8 + 255) / 256, 256, 0, stream>>>(
            x, w_attn, w_proj, xb, wab, wpb);
    }

    // 1) QKV projection (bf16 MFMA, 128x128, BK=32, depth-2 prefetch)
    {
        dim3 grid(M_ / 128, C3 / 128);
        gemm_nt_mfma<u16><<<grid, 256, 0, stream>>>(xb, wab, qkvb, C3, C_);
    }

    // 2a) KV-split attention partials (1728 blocks, 128 q/block, 256-key chunks)
    {
        dim3 grid(NSLOT, H_, B_);
        attn_partial<<<grid, 256, 0, stream>>>(qkvb, po, pl);
    }
    // 2b) combine + normalize
    {
        dim3 grid(W_ / 128, H_, B_);
        attn_combine<<<grid, 256, 0, stream>>>(po, pl, aob);
    }

    // 3) Output projection: out = aob @ wpb^T (fp32 out)
    {
        dim3 grid(M_ / 128, C_ / 128);
        gemm_nt_mfma<float><<<grid, 256, 0, stream>>>(aob, wpb, out, C_, C_);
    }
}

// Round 20
// 113.957 us; speedup vs baseline: 1.0683x; 1.0601x over previous
//
#include <hip/hip_runtime.h>

// Problem constants (B=2, W=2048, C=768, H=12, head dim 64)
constexpr int B_  = 2;
constexpr int W_  = 2048;
constexpr int C_  = 768;
constexpr int H_  = 12;
constexpr int HD  = 64;
constexpr int C3  = 3 * C_;           // 2304
constexpr int M_  = B_ * W_;          // 4096
constexpr int NSLOT = 72;             // (128q-qtile, 256key-chunk) pairs/(b,h)

typedef float  f32x4 __attribute__((ext_vector_type(4)));
typedef short  s16x8 __attribute__((ext_vector_type(8)));
typedef short  s16x4 __attribute__((ext_vector_type(4)));
typedef unsigned short u16;
typedef unsigned int   u32;

// fp32 -> bf16 (round-to-nearest-even), bit pattern as ushort
__device__ __forceinline__ u16 f2bf(float f) {
    unsigned int u = __float_as_uint(f);
    u += 0x7FFFu + ((u >> 16) & 1u);
    return (u16)(u >> 16);
}
__device__ __forceinline__ float bf2f(u16 v) {
    return __uint_as_float(((u32)v) << 16);
}

// async global->LDS, 16 bytes per lane. LDS dest = wave-uniform base + lane*16.
__device__ __forceinline__ void gload_lds16(const u16* g, u16* l) {
    __builtin_amdgcn_global_load_lds(
        (const __attribute__((address_space(1))) unsigned int*)g,
        (__attribute__((address_space(3))) unsigned int*)l, 16, 0, 0);
}

// ---------------------------------------------------------------------------
// fp32 -> bf16 bulk convert, all three tensors in one launch (8 elems/thread)
// ---------------------------------------------------------------------------
__global__ __launch_bounds__(256)
void cvt_all(const float* __restrict__ x, const float* __restrict__ wa,
             const float* __restrict__ wp, u16* __restrict__ xb,
             u16* __restrict__ wab, u16* __restrict__ wpb)
{
    const int n0 = M_ * C_ / 8;
    const int n1 = n0 + C3 * C_ / 8;
    const int n2 = n1 + C_ * C_ / 8;
    int i = blockIdx.x * 256 + threadIdx.x;
    const float* s; u16* d; int j;
    if (i < n0)      { s = x;  d = xb;  j = i; }
    else if (i < n1) { s = wa; d = wab; j = i - n0; }
    else if (i < n2) { s = wp; d = wpb; j = i - n1; }
    else return;
    const float4 a = reinterpret_cast<const float4*>(s)[j * 2];
    const float4 b = reinterpret_cast<const float4*>(s)[j * 2 + 1];
    s16x8 v;
    v[0] = (short)f2bf(a.x); v[1] = (short)f2bf(a.y);
    v[2] = (short)f2bf(a.z); v[3] = (short)f2bf(a.w);
    v[4] = (short)f2bf(b.x); v[5] = (short)f2bf(b.y);
    v[6] = (short)f2bf(b.z); v[7] = (short)f2bf(b.w);
    reinterpret_cast<s16x8*>(d)[j] = v;
}

// ---------------------------------------------------------------------------
// bf16 NT GEMM via MFMA (round-17 kernel, unchanged): 128x128, BK=32,
// triple-buffered depth-2 prefetch with counted vmcnt.
// ---------------------------------------------------------------------------
__device__ __forceinline__ void store_out(u16*  p, float v) { *p = f2bf(v); }
__device__ __forceinline__ void store_out(float* p, float v) { *p = v; }

template <typename OutT>
__global__ __launch_bounds__(256)
void gemm_nt_mfma(const u16* __restrict__ A, const u16* __restrict__ Bm,
                  OutT* __restrict__ Y, int Ndim, int Kdim)
{
    __shared__ __align__(16) u16 As[3][128 * 32];
    __shared__ __align__(16) u16 Bs[3][128 * 32];

    const int t  = threadIdx.x;
    const int w  = t >> 6;
    const int l  = t & 63;
    const int lg = l >> 4;
    const int ln = l & 15;
    const int wm = w >> 1;
    const int wn = w & 1;
    const int m0 = blockIdx.x * 128;
    const int n0 = blockIdx.y * 128;

    f32x4 acc[4][4];
    #pragma unroll
    for (int mi = 0; mi < 4; ++mi)
        #pragma unroll
        for (int ni = 0; ni < 4; ++ni)
            acc[mi][ni] = (f32x4){0.f, 0.f, 0.f, 0.f};

    size_t off[2];
    #pragma unroll
    for (int it = 0; it < 2; ++it) {
        const int c  = t + it * 256;
        off[it] = (size_t)((c >> 6) * 16 + (c & 15)) * Kdim + ((c >> 4) & 3) * 8;
    }

    #define GEMM_STAGE(buf, k0s)                                              \
        _Pragma("unroll")                                                     \
        for (int it = 0; it < 2; ++it) {                                      \
            gload_lds16(A  + (size_t)m0 * Kdim + (k0s) + off[it],             \
                        &As[buf][(size_t)(it * 256 + w * 64) * 8]);           \
            gload_lds16(Bm + (size_t)n0 * Kdim + (k0s) + off[it],             \
                        &Bs[buf][(size_t)(it * 256 + w * 64) * 8]);           \
        }

    GEMM_STAGE(0, 0)
    GEMM_STAGE(1, 32)

    int cur = 0;
    for (int k0 = 0; k0 < Kdim; k0 += 32) {
        if (k0 + 32 < Kdim)
            asm volatile("s_waitcnt vmcnt(4)" ::: "memory");
        else
            asm volatile("s_waitcnt vmcnt(0)" ::: "memory");
        __builtin_amdgcn_s_barrier();

        const int nx2 = (cur + 2 >= 3) ? cur - 1 : cur + 2;
        if (k0 + 64 < Kdim) { GEMM_STAGE(nx2, k0 + 64) }

        s16x8 af[4], bf[4];
        #pragma unroll
        for (int mi = 0; mi < 4; ++mi)
            af[mi] = *reinterpret_cast<const s16x8*>(
                &As[cur][(size_t)((wm * 4 + mi) * 64 + l) * 8]);
        #pragma unroll
        for (int ni = 0; ni < 4; ++ni)
            bf[ni] = *reinterpret_cast<const s16x8*>(
                &Bs[cur][(size_t)((wn * 4 + ni) * 64 + l) * 8]);
        #pragma unroll
        for (int mi = 0; mi < 4; ++mi)
            #pragma unroll
            for (int ni = 0; ni < 4; ++ni)
                acc[mi][ni] = __builtin_amdgcn_mfma_f32_16x16x32_bf16(
                    af[mi], bf[ni], acc[mi][ni], 0, 0, 0);

        cur = (cur == 2) ? 0 : cur + 1;
    }
    #undef GEMM_STAGE

    #pragma unroll
    for (int mi = 0; mi < 4; ++mi) {
        const int row = m0 + wm * 64 + mi * 16 + lg * 4;
        #pragma unroll
        for (int ni = 0; ni < 4; ++ni) {
            const int col = n0 + wn * 64 + ni * 16 + ln;
            #pragma unroll
            for (int r = 0; r < 4; ++r)
                store_out(&Y[(size_t)(row + r) * Ndim + col], acc[mi][ni][r]);
        }
    }
}

// ---------------------------------------------------------------------------
// KV-split MFMA causal flash attention, partial pass (round-19 kernel,
// verbatim): 128 q/block (2 m-frags/wave, shared kf/vf reads), 256-key
// chunks -> 72 slots/(b,h) = 1728 blocks, worst block 4 tiles.
// ---------------------------------------------------------------------------
__global__ __launch_bounds__(256)
void attn_partial(const u16* __restrict__ qkv, u16* __restrict__ po,
                  float* __restrict__ pl)
{
    __shared__ __align__(16) unsigned char KsB[64 * 128];       // 8 KiB
    __shared__ __align__(16) unsigned char VtB[64 * 144];       // 9 KiB

    const int t  = threadIdx.x;
    const int w  = t >> 6;
    const int l  = t & 63;
    const int lg = l >> 4;
    const int ln = l & 15;
    const int p  = (NSLOT - 1) - (int)blockIdx.x;   // biggest-first
    const int h  = blockIdx.y;
    const int b  = blockIdx.z;

    int qt = 0, cumv = 0;
    while (cumv + ((qt >> 1) + 1) <= p) { cumv += (qt >> 1) + 1; ++qt; }
    const int ck = p - cumv;

    const int qb  = qt * 128;
    const int q0w = qb + w * 32;
    const int g0  = ck * 4;
    const int g1  = min(2 * (qt + 1), g0 + 4);
    const int slot = (b * H_ + h) * NSLOT + p;

    const u16* base  = qkv + (size_t)(b * W_) * C3;
    const u16* kbase = base + C_ + h * HD;
    const u16* vbase = base + 2 * C_ + h * HD;

    s16x8 qf[2][2];
    #pragma unroll
    for (int m = 0; m < 2; ++m) {
        const u16* qrow = base + (size_t)(q0w + m * 16 + ln) * C3 + h * HD;
        #pragma unroll
        for (int kc = 0; kc < 2; ++kc)
            qf[m][kc] = *reinterpret_cast<const s16x8*>(&qrow[kc * 32 + lg * 8]);
    }

    s16x8 onesf;
    {
        const short v1 = (ln == 0) ? (short)0x3F80 : (short)0;
        #pragma unroll
        for (int i = 0; i < 8; ++i) onesf[i] = v1;
    }

    f32x4 o[2][4];
    #pragma unroll
    for (int m = 0; m < 2; ++m)
        #pragma unroll
        for (int i = 0; i < 4; ++i) o[m][i] = (f32x4){0.f, 0.f, 0.f, 0.f};
    f32x4 o4[2] = { (f32x4){0.f,0.f,0.f,0.f}, (f32x4){0.f,0.f,0.f,0.f} };

    const float c1 = 0.18033688011112042f;   // (1/8) * log2(e)
    const float c2 = 17.312340490667562f;    // 12  * log2(e)

    const size_t sk_off = (size_t)((t >> 7) * 16 + (t & 15)) * C3
                        + ((t >> 6) & 1) * 32 + ((t >> 4) & 3) * 8;
    const bool vstage = (t < 128);
    const int vrun = (t >> 4) & 7;
    const int vK0  = (vrun >> 2) * 32 + (vrun & 3) * 4;
    const int vdq  = (t & 15) * 4;
    const int kfb  = l * 16;

    s16x8 kr[2];
    s16x4 vr[8];

    {
        const int s0 = g0 * 64;
        const u16* ks = kbase + (size_t)s0 * C3 + sk_off;
        kr[0] = *reinterpret_cast<const s16x8*>(ks);
        kr[1] = *reinterpret_cast<const s16x8*>(ks + (size_t)32 * C3);
        if (vstage) {
            const u16* vsrc = vbase + (size_t)(s0 + vK0) * C3 + vdq;
            #pragma unroll
            for (int e = 0; e < 8; ++e)
                vr[e] = *reinterpret_cast<const s16x4*>(
                    &vsrc[(size_t)((e >> 2) * 16 + (e & 3)) * C3]);
        }
    }

    for (int g = g0; g < g1; ++g) {
        const int s0 = g * 64;

        __syncthreads();

        *reinterpret_cast<s16x8*>(KsB + t * 16)         = kr[0];
        *reinterpret_cast<s16x8*>(KsB + (t + 256) * 16) = kr[1];
        if (vstage) {
            #pragma unroll
            for (int j = 0; j < 4; ++j) {
                s16x8 pk = { vr[0][j], vr[1][j], vr[2][j], vr[3][j],
                             vr[4][j], vr[5][j], vr[6][j], vr[7][j] };
                *reinterpret_cast<s16x8*>(
                    VtB + (vdq + j) * 144 + vrun * 16) = pk;
            }
        }

        if (g + 1 < g1) {
            const int s1 = s0 + 64;
            const u16* ks = kbase + (size_t)s1 * C3 + sk_off;
            kr[0] = *reinterpret_cast<const s16x8*>(ks);
            kr[1] = *reinterpret_cast<const s16x8*>(ks + (size_t)32 * C3);
            if (vstage) {
                const u16* vsrc = vbase + (size_t)(s1 + vK0) * C3 + vdq;
                #pragma unroll
                for (int e = 0; e < 8; ++e)
                    vr[e] = *reinterpret_cast<const s16x4*>(
                        &vsrc[(size_t)((e >> 2) * 16 + (e & 3)) * C3]);
            }
        }

        __syncthreads();

        #pragma unroll
        for (int c = 0; c < 2; ++c) {
            if (s0 + c * 32 <= q0w + 31) {
                const bool act0 = (s0 + c * 32 <= q0w + 15);
                float pt[2][2][4];
                #pragma unroll
                for (int n2 = 0; n2 < 2; ++n2) {
                    const unsigned char* kfrag = KsB + (c * 2 + n2) * 2048 + kfb;
                    s16x8 kf0 = *reinterpret_cast<const s16x8*>(kfrag);
                    s16x8 kf1 = *reinterpret_cast<const s16x8*>(kfrag + 1024);
                    #pragma unroll
                    for (int m = 0; m < 2; ++m) {
                        if (m == 1 || act0) {
                            f32x4 s = (f32x4){0.f, 0.f, 0.f, 0.f};
                            __builtin_amdgcn_s_setprio(1);
                            s = __builtin_amdgcn_mfma_f32_16x16x32_bf16(
                                kf0, qf[m][0], s, 0, 0, 0);
                            s = __builtin_amdgcn_mfma_f32_16x16x32_bf16(
                                kf1, qf[m][1], s, 0, 0, 0);
                            __builtin_amdgcn_s_setprio(0);
                            const int kg0   = s0 + c * 32 + n2 * 16 + lg * 4;
                            const int klast = s0 + c * 32 + n2 * 16 + 15;
                            const int qbase = q0w + m * 16;
                            if (klast <= qbase) {
                                #pragma unroll
                                for (int r = 0; r < 4; ++r)
                                    pt[m][n2][r] = exp2f(fmaf(s[r], c1, -c2));
                            } else {
                                const int qg = qbase + ln;
                                #pragma unroll
                                for (int r = 0; r < 4; ++r)
                                    pt[m][n2][r] = (kg0 + r <= qg)
                                              ? exp2f(fmaf(s[r], c1, -c2)) : 0.0f;
                            }
                        }
                    }
                }
                s16x8 vf[4];
                #pragma unroll
                for (int dt = 0; dt < 4; ++dt)
                    vf[dt] = *reinterpret_cast<const s16x8*>(
                        VtB + (dt * 16 + ln) * 144 + c * 64 + lg * 16);
                #pragma unroll
                for (int m = 0; m < 2; ++m) {
                    if (m == 1 || act0) {
                        union { s16x8 v; u32 wd[4]; } afu;
                        asm("v_cvt_pk_bf16_f32 %0, %1, %2"
                            : "=v"(afu.wd[0]) : "v"(pt[m][0][0]), "v"(pt[m][0][1]));
                        asm("v_cvt_pk_bf16_f32 %0, %1, %2"
                            : "=v"(afu.wd[1]) : "v"(pt[m][0][2]), "v"(pt[m][0][3]));
                        asm("v_cvt_pk_bf16_f32 %0, %1, %2"
                            : "=v"(afu.wd[2]) : "v"(pt[m][1][0]), "v"(pt[m][1][1]));
                        asm("v_cvt_pk_bf16_f32 %0, %1, %2"
                            : "=v"(afu.wd[3]) : "v"(pt[m][1][2]), "v"(pt[m][1][3]));
                        const s16x8 af = afu.v;
                        __builtin_amdgcn_s_setprio(1);
                        #pragma unroll
                        for (int dt = 0; dt < 4; ++dt)
                            o[m][dt] = __builtin_amdgcn_mfma_f32_16x16x32_bf16(
                                af, vf[dt], o[m][dt], 0, 0, 0);
                        o4[m] = __builtin_amdgcn_mfma_f32_16x16x32_bf16(
                            af, onesf, o4[m], 0, 0, 0);
                        __builtin_amdgcn_s_setprio(0);
                    }
                }
            }
        }
    }

    #pragma unroll
    for (int m = 0; m < 2; ++m) {
        if (ln == 0) {
            #pragma unroll
            for (int r = 0; r < 4; ++r)
                pl[(size_t)slot * 128 + w * 32 + m * 16 + lg * 4 + r] = o4[m][r];
        }
        u16* os = po + (size_t)slot * 8192;
        #pragma unroll
        for (int r = 0; r < 4; ++r)
            #pragma unroll
            for (int dt = 0; dt < 4; ++dt)
                os[(w * 32 + m * 16 + lg * 4 + r) * 64 + dt * 16 + ln] =
                    f2bf(o[m][dt][r]);
    }
}

// ---------------------------------------------------------------------------
// Combine pass v2, PARALLELIZED: 1536 blocks (16 qtiles x 4 rowgroups x H x B).
// Each block: 32 q-rows x 64 dims; thread owns one row's 8 dims (16B loads).
// ---------------------------------------------------------------------------
__global__ __launch_bounds__(256)
void attn_combine(const u16* __restrict__ po, const float* __restrict__ pl,
                  u16* __restrict__ aob)
{
    const int qt = blockIdx.x >> 2;     // 0..15
    const int rg = blockIdx.x & 3;      // row group (32 rows)
    const int h  = blockIdx.y;
    const int b  = blockIdx.z;
    const int a  = qt >> 1;
    const int nc = a + 1;
    const int cum = (qt & 1) ? (a + 1) * (a + 1) : a * (a + 1);
    const int slot0 = (b * H_ + h) * NSLOT + cum;

    const int tid = threadIdx.x;
    const int i   = rg * 32 + (tid >> 3);   // query row in tile (0..127)
    const int d0  = (tid & 7) * 8;          // 8 dims per thread

    float acc[8] = {};
    float lt = 0.0f;
    for (int c = 0; c < nc; ++c) {
        const u16* os = po + (size_t)(slot0 + c) * 8192 + i * 64 + d0;
        s16x8 vv = *reinterpret_cast<const s16x8*>(os);
        #pragma unroll
        for (int e = 0; e < 8; ++e) acc[e] += bf2f((u16)vv[e]);
        lt += pl[(size_t)(slot0 + c) * 128 + i];
    }
    const float inv = 1.0f / lt;

    u16* dst = aob + (size_t)(b * W_ + qt * 128 + i) * C_ + h * HD + d0;
    s16x8 ov;
    #pragma unroll
    for (int e = 0; e < 8; ++e) ov[e] = (short)f2bf(acc[e] * inv);
    *reinterpret_cast<s16x8*>(dst) = ov;
}

// ---------------------------------------------------------------------------
extern "C" void kernel_launch(void* const* d_in, const int* in_sizes, int n_in,
                              void* d_out, int out_size, void* d_ws, size_t ws_size,
                              hipStream_t stream)
{
    const float* x      = (const float*)d_in[0];  // [B,W,C]
    const float* w_attn = (const float*)d_in[1];  // [3C,C]
    const float* w_proj = (const float*)d_in[2];  // [C,C]
    float* out = (float*)d_out;                   // [B,W,C]

    u16* xb   = (u16*)d_ws;                       // [M,  C]
    u16* wab  = xb   + (size_t)M_ * C_;           // [3C, C]
    u16* wpb  = wab  + (size_t)C3 * C_;           // [C,  C]
    u16* qkvb = wpb  + (size_t)C_ * C_;           // [M, 3C]
    u16* aob  = qkvb + (size_t)M_ * C3;           // [M,  C]
    u16* po   = aob  + (size_t)M_ * C_;           // [1728][8192] bf16
    float* pl = (float*)(po + (size_t)B_ * H_ * NSLOT * 8192);  // [1728][128]

    // 0) fp32 -> bf16 conversions (single launch)
    {
        const int total8 = (M_ * C_ + C3 * C_ + C_ * C_) / 8;
        cvt_all<<<(total8 + 255) / 256, 256, 0, stream>>>(
            x, w_attn, w_proj, xb, wab, wpb);
    }

    // 1) QKV projection (bf16 MFMA, 128x128, BK=32, depth-2 prefetch)
    {
        dim3 grid(M_ / 128, C3 / 128);
        gemm_nt_mfma<u16><<<grid, 256, 0, stream>>>(xb, wab, qkvb, C3, C_);
    }

    // 2a) KV-split attention partials (1728 blocks, 128 q/block, 256-key chunks)
    {
        dim3 grid(NSLOT, H_, B_);
        attn_partial<<<grid, 256, 0, stream>>>(qkvb, po, pl);
    }
    // 2b) combine + normalize (parallel: 1536 blocks)
    {
        dim3 grid((W_ / 128) * 4, H_, B_);
        attn_combine<<<grid, 256, 0, stream>>>(po, pl, aob);
    }

    // 3) Output projection: out = aob @ wpb^T (fp32 out)
    {
        dim3 grid(M_ / 128, C_ / 128);
        gemm_nt_mfma<float><<<grid, 256, 0, stream>>>(aob, wpb, out, C_, C_);
    }
}

// Round 21
// 109.903 us; speedup vs baseline: 1.1077x; 1.0369x over previous
//
#include <hip/hip_runtime.h>

// Problem constants (B=2, W=2048, C=768, H=12, head dim 64)
constexpr int B_  = 2;
constexpr int W_  = 2048;
constexpr int C_  = 768;
constexpr int H_  = 12;
constexpr int HD  = 64;
constexpr int C3  = 3 * C_;           // 2304
constexpr int M_  = B_ * W_;          // 4096
constexpr int NSLOT = 72;             // (128q-qtile, 256key-chunk) pairs/(b,h)

typedef float  f32x4 __attribute__((ext_vector_type(4)));
typedef short  s16x8 __attribute__((ext_vector_type(8)));
typedef short  s16x4 __attribute__((ext_vector_type(4)));
typedef unsigned short u16;
typedef unsigned int   u32;

// fp32 -> bf16 (round-to-nearest-even), bit pattern as ushort
__device__ __forceinline__ u16 f2bf(float f) {
    unsigned int u = __float_as_uint(f);
    u += 0x7FFFu + ((u >> 16) & 1u);
    return (u16)(u >> 16);
}
__device__ __forceinline__ float bf2f(u16 v) {
    return __uint_as_float(((u32)v) << 16);
}

// async global->LDS, 16 bytes per lane. LDS dest = wave-uniform base + lane*16.
__device__ __forceinline__ void gload_lds16(const u16* g, u16* l) {
    __builtin_amdgcn_global_load_lds(
        (const __attribute__((address_space(1))) unsigned int*)g,
        (__attribute__((address_space(3))) unsigned int*)l, 16, 0, 0);
}

// ---------------------------------------------------------------------------
// fp32 -> bf16 bulk convert, all three tensors in one launch (8 elems/thread)
// ---------------------------------------------------------------------------
__global__ __launch_bounds__(256)
void cvt_all(const float* __restrict__ x, const float* __restrict__ wa,
             const float* __restrict__ wp, u16* __restrict__ xb,
             u16* __restrict__ wab, u16* __restrict__ wpb)
{
    const int n0 = M_ * C_ / 8;
    const int n1 = n0 + C3 * C_ / 8;
    const int n2 = n1 + C_ * C_ / 8;
    int i = blockIdx.x * 256 + threadIdx.x;
    const float* s; u16* d; int j;
    if (i < n0)      { s = x;  d = xb;  j = i; }
    else if (i < n1) { s = wa; d = wab; j = i - n0; }
    else if (i < n2) { s = wp; d = wpb; j = i - n1; }
    else return;
    const float4 a = reinterpret_cast<const float4*>(s)[j * 2];
    const float4 b = reinterpret_cast<const float4*>(s)[j * 2 + 1];
    s16x8 v;
    v[0] = (short)f2bf(a.x); v[1] = (short)f2bf(a.y);
    v[2] = (short)f2bf(a.z); v[3] = (short)f2bf(a.w);
    v[4] = (short)f2bf(b.x); v[5] = (short)f2bf(b.y);
    v[6] = (short)f2bf(b.z); v[7] = (short)f2bf(b.w);
    reinterpret_cast<s16x8*>(d)[j] = v;
}

// ---------------------------------------------------------------------------
// bf16 NT GEMM via MFMA, v6: BM x 128 tile (BM template: 128 for GEMM1,
// 64 for GEMM2), BK=32, DOUBLE-BUFFERED (round-16 schedule — the measured
// best: depth-2/48KiB regressed GEMM1 ~10us via 5->3 blocks/CU residency).
// BM=128: LDS 32 KiB -> 5 blocks/CU. BM=64: LDS 24 KiB -> 6 blocks/CU and
// GEMM2's grid doubles to 384 blocks (was 0.75 blocks/CU -> CUs idle).
// One __syncthreads per K-step; next tile's gloads issued before compute.
// Chunk c: fr=c>>6, kc=(c>>4)&3, rr=c&15 -> row fr*16+rr, k=kc*8.
// Fragment fr read = chunks [fr*64 .. fr*64+64) = contiguous 1 KiB.
// ---------------------------------------------------------------------------
__device__ __forceinline__ void store_out(u16*  p, float v) { *p = f2bf(v); }
__device__ __forceinline__ void store_out(float* p, float v) { *p = v; }

template <int BM, typename OutT>
__global__ __launch_bounds__(256)
void gemm_nt_mfma(const u16* __restrict__ A, const u16* __restrict__ Bm,
                  OutT* __restrict__ Y, int Ndim, int Kdim)
{
    constexpr int MF  = BM / 32;           // m-frags per wave (4 or 2)
    constexpr int AIT = BM / 64;           // A staging iters (2 or 1)
    __shared__ __align__(16) u16 As[2][BM * 32];
    __shared__ __align__(16) u16 Bs[2][128 * 32];

    const int t  = threadIdx.x;
    const int w  = t >> 6;
    const int l  = t & 63;
    const int lg = l >> 4;
    const int ln = l & 15;
    const int wm = w >> 1;
    const int wn = w & 1;
    const int m0 = blockIdx.x * BM;
    const int n0 = blockIdx.y * 128;

    f32x4 acc[MF][4];
    #pragma unroll
    for (int mi = 0; mi < MF; ++mi)
        #pragma unroll
        for (int ni = 0; ni < 4; ++ni)
            acc[mi][ni] = (f32x4){0.f, 0.f, 0.f, 0.f};

    // per-thread chunk source offsets (chunks c = t + it*256)
    size_t off[2];
    #pragma unroll
    for (int it = 0; it < 2; ++it) {
        const int c  = t + it * 256;
        off[it] = (size_t)((c >> 6) * 16 + (c & 15)) * Kdim + ((c >> 4) & 3) * 8;
    }

    #define GEMM_STAGE(buf, k0s)                                              \
        _Pragma("unroll")                                                     \
        for (int it = 0; it < AIT; ++it)                                      \
            gload_lds16(A  + (size_t)m0 * Kdim + (k0s) + off[it],             \
                        &As[buf][(size_t)(it * 256 + w * 64) * 8]);           \
        _Pragma("unroll")                                                     \
        for (int it = 0; it < 2; ++it)                                        \
            gload_lds16(Bm + (size_t)n0 * Kdim + (k0s) + off[it],             \
                        &Bs[buf][(size_t)(it * 256 + w * 64) * 8]);

    GEMM_STAGE(0, 0)
    __syncthreads();

    int cur = 0;
    for (int k0 = 0; k0 < Kdim; k0 += 32) {
        if (k0 + 32 < Kdim) { GEMM_STAGE(cur ^ 1, k0 + 32) }

        s16x8 af[MF], bf[4];
        #pragma unroll
        for (int mi = 0; mi < MF; ++mi)
            af[mi] = *reinterpret_cast<const s16x8*>(
                &As[cur][(size_t)((wm * MF + mi) * 64 + l) * 8]);
        #pragma unroll
        for (int ni = 0; ni < 4; ++ni)
            bf[ni] = *reinterpret_cast<const s16x8*>(
                &Bs[cur][(size_t)((wn * 4 + ni) * 64 + l) * 8]);
        #pragma unroll
        for (int mi = 0; mi < MF; ++mi)
            #pragma unroll
            for (int ni = 0; ni < 4; ++ni)
                acc[mi][ni] = __builtin_amdgcn_mfma_f32_16x16x32_bf16(
                    af[mi], bf[ni], acc[mi][ni], 0, 0, 0);

        __syncthreads();   // drain lands one compute phase after issue
        cur ^= 1;
    }
    #undef GEMM_STAGE

    #pragma unroll
    for (int mi = 0; mi < MF; ++mi) {
        const int row = m0 + wm * (MF * 16) + mi * 16 + lg * 4;
        #pragma unroll
        for (int ni = 0; ni < 4; ++ni) {
            const int col = n0 + wn * 64 + ni * 16 + ln;
            #pragma unroll
            for (int r = 0; r < 4; ++r)
                store_out(&Y[(size_t)(row + r) * Ndim + col], acc[mi][ni][r]);
        }
    }
}

// ---------------------------------------------------------------------------
// KV-split MFMA causal flash attention, partial pass (round-19/20 kernel,
// verbatim): 128 q/block (2 m-frags/wave, shared kf/vf reads), 256-key
// chunks -> 72 slots/(b,h) = 1728 blocks, worst block 4 tiles.
// ---------------------------------------------------------------------------
__global__ __launch_bounds__(256)
void attn_partial(const u16* __restrict__ qkv, u16* __restrict__ po,
                  float* __restrict__ pl)
{
    __shared__ __align__(16) unsigned char KsB[64 * 128];       // 8 KiB
    __shared__ __align__(16) unsigned char VtB[64 * 144];       // 9 KiB

    const int t  = threadIdx.x;
    const int w  = t >> 6;
    const int l  = t & 63;
    const int lg = l >> 4;
    const int ln = l & 15;
    const int p  = (NSLOT - 1) - (int)blockIdx.x;   // biggest-first
    const int h  = blockIdx.y;
    const int b  = blockIdx.z;

    int qt = 0, cumv = 0;
    while (cumv + ((qt >> 1) + 1) <= p) { cumv += (qt >> 1) + 1; ++qt; }
    const int ck = p - cumv;

    const int qb  = qt * 128;
    const int q0w = qb + w * 32;
    const int g0  = ck * 4;
    const int g1  = min(2 * (qt + 1), g0 + 4);
    const int slot = (b * H_ + h) * NSLOT + p;

    const u16* base  = qkv + (size_t)(b * W_) * C3;
    const u16* kbase = base + C_ + h * HD;
    const u16* vbase = base + 2 * C_ + h * HD;

    s16x8 qf[2][2];
    #pragma unroll
    for (int m = 0; m < 2; ++m) {
        const u16* qrow = base + (size_t)(q0w + m * 16 + ln) * C3 + h * HD;
        #pragma unroll
        for (int kc = 0; kc < 2; ++kc)
            qf[m][kc] = *reinterpret_cast<const s16x8*>(&qrow[kc * 32 + lg * 8]);
    }

    s16x8 onesf;
    {
        const short v1 = (ln == 0) ? (short)0x3F80 : (short)0;
        #pragma unroll
        for (int i = 0; i < 8; ++i) onesf[i] = v1;
    }

    f32x4 o[2][4];
    #pragma unroll
    for (int m = 0; m < 2; ++m)
        #pragma unroll
        for (int i = 0; i < 4; ++i) o[m][i] = (f32x4){0.f, 0.f, 0.f, 0.f};
    f32x4 o4[2] = { (f32x4){0.f,0.f,0.f,0.f}, (f32x4){0.f,0.f,0.f,0.f} };

    const float c1 = 0.18033688011112042f;   // (1/8) * log2(e)
    const float c2 = 17.312340490667562f;    // 12  * log2(e)

    const size_t sk_off = (size_t)((t >> 7) * 16 + (t & 15)) * C3
                        + ((t >> 6) & 1) * 32 + ((t >> 4) & 3) * 8;
    const bool vstage = (t < 128);
    const int vrun = (t >> 4) & 7;
    const int vK0  = (vrun >> 2) * 32 + (vrun & 3) * 4;
    const int vdq  = (t & 15) * 4;
    const int kfb  = l * 16;

    s16x8 kr[2];
    s16x4 vr[8];

    {
        const int s0 = g0 * 64;
        const u16* ks = kbase + (size_t)s0 * C3 + sk_off;
        kr[0] = *reinterpret_cast<const s16x8*>(ks);
        kr[1] = *reinterpret_cast<const s16x8*>(ks + (size_t)32 * C3);
        if (vstage) {
            const u16* vsrc = vbase + (size_t)(s0 + vK0) * C3 + vdq;
            #pragma unroll
            for (int e = 0; e < 8; ++e)
                vr[e] = *reinterpret_cast<const s16x4*>(
                    &vsrc[(size_t)((e >> 2) * 16 + (e & 3)) * C3]);
        }
    }

    for (int g = g0; g < g1; ++g) {
        const int s0 = g * 64;

        __syncthreads();

        *reinterpret_cast<s16x8*>(KsB + t * 16)         = kr[0];
        *reinterpret_cast<s16x8*>(KsB + (t + 256) * 16) = kr[1];
        if (vstage) {
            #pragma unroll
            for (int j = 0; j < 4; ++j) {
                s16x8 pk = { vr[0][j], vr[1][j], vr[2][j], vr[3][j],
                             vr[4][j], vr[5][j], vr[6][j], vr[7][j] };
                *reinterpret_cast<s16x8*>(
                    VtB + (vdq + j) * 144 + vrun * 16) = pk;
            }
        }

        if (g + 1 < g1) {
            const int s1 = s0 + 64;
            const u16* ks = kbase + (size_t)s1 * C3 + sk_off;
            kr[0] = *reinterpret_cast<const s16x8*>(ks);
            kr[1] = *reinterpret_cast<const s16x8*>(ks + (size_t)32 * C3);
            if (vstage) {
                const u16* vsrc = vbase + (size_t)(s1 + vK0) * C3 + vdq;
                #pragma unroll
                for (int e = 0; e < 8; ++e)
                    vr[e] = *reinterpret_cast<const s16x4*>(
                        &vsrc[(size_t)((e >> 2) * 16 + (e & 3)) * C3]);
            }
        }

        __syncthreads();

        #pragma unroll
        for (int c = 0; c < 2; ++c) {
            if (s0 + c * 32 <= q0w + 31) {
                const bool act0 = (s0 + c * 32 <= q0w + 15);
                float pt[2][2][4];
                #pragma unroll
                for (int n2 = 0; n2 < 2; ++n2) {
                    const unsigned char* kfrag = KsB + (c * 2 + n2) * 2048 + kfb;
                    s16x8 kf0 = *reinterpret_cast<const s16x8*>(kfrag);
                    s16x8 kf1 = *reinterpret_cast<const s16x8*>(kfrag + 1024);
                    #pragma unroll
                    for (int m = 0; m < 2; ++m) {
                        if (m == 1 || act0) {
                            f32x4 s = (f32x4){0.f, 0.f, 0.f, 0.f};
                            __builtin_amdgcn_s_setprio(1);
                            s = __builtin_amdgcn_mfma_f32_16x16x32_bf16(
                                kf0, qf[m][0], s, 0, 0, 0);
                            s = __builtin_amdgcn_mfma_f32_16x16x32_bf16(
                                kf1, qf[m][1], s, 0, 0, 0);
                            __builtin_amdgcn_s_setprio(0);
                            const int kg0   = s0 + c * 32 + n2 * 16 + lg * 4;
                            const int klast = s0 + c * 32 + n2 * 16 + 15;
                            const int qbase = q0w + m * 16;
                            if (klast <= qbase) {
                                #pragma unroll
                                for (int r = 0; r < 4; ++r)
                                    pt[m][n2][r] = exp2f(fmaf(s[r], c1, -c2));
                            } else {
                                const int qg = qbase + ln;
                                #pragma unroll
                                for (int r = 0; r < 4; ++r)
                                    pt[m][n2][r] = (kg0 + r <= qg)
                                              ? exp2f(fmaf(s[r], c1, -c2)) : 0.0f;
                            }
                        }
                    }
                }
                s16x8 vf[4];
                #pragma unroll
                for (int dt = 0; dt < 4; ++dt)
                    vf[dt] = *reinterpret_cast<const s16x8*>(
                        VtB + (dt * 16 + ln) * 144 + c * 64 + lg * 16);
                #pragma unroll
                for (int m = 0; m < 2; ++m) {
                    if (m == 1 || act0) {
                        union { s16x8 v; u32 wd[4]; } afu;
                        asm("v_cvt_pk_bf16_f32 %0, %1, %2"
                            : "=v"(afu.wd[0]) : "v"(pt[m][0][0]), "v"(pt[m][0][1]));
                        asm("v_cvt_pk_bf16_f32 %0, %1, %2"
                            : "=v"(afu.wd[1]) : "v"(pt[m][0][2]), "v"(pt[m][0][3]));
                        asm("v_cvt_pk_bf16_f32 %0, %1, %2"
                            : "=v"(afu.wd[2]) : "v"(pt[m][1][0]), "v"(pt[m][1][1]));
                        asm("v_cvt_pk_bf16_f32 %0, %1, %2"
                            : "=v"(afu.wd[3]) : "v"(pt[m][1][2]), "v"(pt[m][1][3]));
                        const s16x8 af = afu.v;
                        __builtin_amdgcn_s_setprio(1);
                        #pragma unroll
                        for (int dt = 0; dt < 4; ++dt)
                            o[m][dt] = __builtin_amdgcn_mfma_f32_16x16x32_bf16(
                                af, vf[dt], o[m][dt], 0, 0, 0);
                        o4[m] = __builtin_amdgcn_mfma_f32_16x16x32_bf16(
                            af, onesf, o4[m], 0, 0, 0);
                        __builtin_amdgcn_s_setprio(0);
                    }
                }
            }
        }
    }

    #pragma unroll
    for (int m = 0; m < 2; ++m) {
        if (ln == 0) {
            #pragma unroll
            for (int r = 0; r < 4; ++r)
                pl[(size_t)slot * 128 + w * 32 + m * 16 + lg * 4 + r] = o4[m][r];
        }
        u16* os = po + (size_t)slot * 8192;
        #pragma unroll
        for (int r = 0; r < 4; ++r)
            #pragma unroll
            for (int dt = 0; dt < 4; ++dt)
                os[(w * 32 + m * 16 + lg * 4 + r) * 64 + dt * 16 + ln] =
                    f2bf(o[m][dt][r]);
    }
}

// ---------------------------------------------------------------------------
// Combine pass v2, PARALLELIZED (round-20, unchanged): 1536 blocks.
// ---------------------------------------------------------------------------
__global__ __launch_bounds__(256)
void attn_combine(const u16* __restrict__ po, const float* __restrict__ pl,
                  u16* __restrict__ aob)
{
    const int qt = blockIdx.x >> 2;     // 0..15
    const int rg = blockIdx.x & 3;      // row group (32 rows)
    const int h  = blockIdx.y;
    const int b  = blockIdx.z;
    const int a  = qt >> 1;
    const int nc = a + 1;
    const int cum = (qt & 1) ? (a + 1) * (a + 1) : a * (a + 1);
    const int slot0 = (b * H_ + h) * NSLOT + cum;

    const int tid = threadIdx.x;
    const int i   = rg * 32 + (tid >> 3);   // query row in tile (0..127)
    const int d0  = (tid & 7) * 8;          // 8 dims per thread

    float acc[8] = {};
    float lt = 0.0f;
    for (int c = 0; c < nc; ++c) {
        const u16* os = po + (size_t)(slot0 + c) * 8192 + i * 64 + d0;
        s16x8 vv = *reinterpret_cast<const s16x8*>(os);
        #pragma unroll
        for (int e = 0; e < 8; ++e) acc[e] += bf2f((u16)vv[e]);
        lt += pl[(size_t)(slot0 + c) * 128 + i];
    }
    const float inv = 1.0f / lt;

    u16* dst = aob + (size_t)(b * W_ + qt * 128 + i) * C_ + h * HD + d0;
    s16x8 ov;
    #pragma unroll
    for (int e = 0; e < 8; ++e) ov[e] = (short)f2bf(acc[e] * inv);
    *reinterpret_cast<s16x8*>(dst) = ov;
}

// ---------------------------------------------------------------------------
extern "C" void kernel_launch(void* const* d_in, const int* in_sizes, int n_in,
                              void* d_out, int out_size, void* d_ws, size_t ws_size,
                              hipStream_t stream)
{
    const float* x      = (const float*)d_in[0];  // [B,W,C]
    const float* w_attn = (const float*)d_in[1];  // [3C,C]
    const float* w_proj = (const float*)d_in[2];  // [C,C]
    float* out = (float*)d_out;                   // [B,W,C]

    u16* xb   = (u16*)d_ws;                       // [M,  C]
    u16* wab  = xb   + (size_t)M_ * C_;           // [3C, C]
    u16* wpb  = wab  + (size_t)C3 * C_;           // [C,  C]
    u16* qkvb = wpb  + (size_t)C_ * C_;           // [M, 3C]
    u16* aob  = qkvb + (size_t)M_ * C3;           // [M,  C]
    u16* po   = aob  + (size_t)M_ * C_;           // [1728][8192] bf16
    float* pl = (float*)(po + (size_t)B_ * H_ * NSLOT * 8192);  // [1728][128]

    // 0) fp32 -> bf16 conversions (single launch)
    {
        const int total8 = (M_ * C_ + C3 * C_ + C_ * C_) / 8;
        cvt_all<<<(total8 + 255) / 256, 256, 0, stream>>>(
            x, w_attn, w_proj, xb, wab, wpb);
    }

    // 1) QKV projection (bf16 MFMA, 128x128, BK=32 2-buffer, 32 KiB LDS)
    {
        dim3 grid(M_ / 128, C3 / 128);   // 576 blocks, 5/CU capacity
        gemm_nt_mfma<128, u16><<<grid, 256, 0, stream>>>(xb, wab, qkvb, C3, C_);
    }

    // 2a) KV-split attention partials (1728 blocks, 128 q/block, 256-key chunks)
    {
        dim3 grid(NSLOT, H_, B_);
        attn_partial<<<grid, 256, 0, stream>>>(qkvb, po, pl);
    }
    // 2b) combine + normalize (parallel: 1536 blocks)
    {
        dim3 grid((W_ / 128) * 4, H_, B_);
        attn_combine<<<grid, 256, 0, stream>>>(po, pl, aob);
    }

    // 3) Output projection (BM=64 -> 384 blocks, 24 KiB LDS): out = aob @ wpb^T
    {
        dim3 grid(M_ / 64, C_ / 128);
        gemm_nt_mfma<64, float><<<grid, 256, 0, stream>>>(aob, wpb, out, C_, C_);
    }
}